// Round 7
// baseline (260.793 us; speedup 1.0000x reference)
//
#include <hip/hip_runtime.h>

constexpr int S_LEN = 2048;
constexpr int D_K   = 64;
constexpr int N_BH  = 32;   // B*H
constexpr int KB    = 64;   // k per chunk

typedef __attribute__((ext_vector_type(8))) short short8;
typedef __attribute__((ext_vector_type(4))) float f32x4;
typedef unsigned short ushort_t;

__device__ __forceinline__ unsigned short f2bf(float f) {
    unsigned int u = __builtin_bit_cast(unsigned int, f);
    u += 0x7fffu + ((u >> 16) & 1u);          // round-to-nearest-even
    return (unsigned short)(u >> 16);
}
__device__ __forceinline__ float bf2f(unsigned short h) {
    unsigned int u = ((unsigned int)h) << 16;
    return __builtin_bit_cast(float, u);
}

// ============================ prep kernels ============================
__global__ __launch_bounds__(256)
void prep_k(const float* __restrict__ K, ushort_t* __restrict__ Kws) {
    const int idx = blockIdx.x * 256 + threadIdx.x;
    const float4* src = (const float4*)K + (size_t)idx * 2;
    float4 a = src[0], b = src[1];
    float x[8] = {a.x, a.y, a.z, a.w, b.x, b.y, b.z, b.w};
    short8 o;
    #pragma unroll
    for (int j = 0; j < 8; ++j) o[j] = (short)f2bf(x[j] * 0.125f);
    *(short8*)(Kws + (size_t)idx * 8) = o;
}

__global__ __launch_bounds__(256)
void prep_v(const float* __restrict__ V, ushort_t* __restrict__ Vws) {
    const int gid = blockIdx.x * 256 + threadIdx.x;
    const int u   = gid & 511;
    const int bc  = gid >> 9;
    const int c   = bc & 31;
    const int bh  = bc >> 5;
    const int kg  = u >> 6;
    const int d   = u & 63;
    const float* vp = V + ((size_t)bh * S_LEN + c * KB + kg * 8) * D_K + d;
    short8 o;
    #pragma unroll
    for (int i = 0; i < 8; ++i) o[i] = (short)f2bf(vp[(size_t)i * D_K]);
    *(short8*)(Vws + ((size_t)(bh * 32 + c) * D_K + d) * KB + kg * 8) = o;
}

// ============================ main kernel =============================
// 1024 blocks x 256 threads (4 waves). Each block: ONE 64-row q-tile.
// NO K/V LDS staging: K/V per head is 512 KB bf16 and L2-resident (XCD-pinned:
// bh = (m&3)*8 + (bx&7) puts 4 heads = 2 MB on each XCD's L2). Fragments are
// read directly from Kws/Vws as per-lane 16 B loads -> ZERO __syncthreads in
// the chunk loops; only wave-private Plds remains. 16 free-running waves/CU
// hide L2/exp/store latency that the barrier-lockstep versions serialized.
// Per-CU tile mix {j0, 15-j0, 16+j0, 31-j0} keeps total chunk-units = 66.
__global__ __launch_bounds__(256, 4)
void sdpa_main(const float* __restrict__ Q, const ushort_t* __restrict__ Kws,
               const ushort_t* __restrict__ Vws, float* __restrict__ out)
{
    __shared__ __align__(16) ushort_t Plds[4][1024];   // per-wave 16x64, XOR-swizzled

    const int tid = threadIdx.x;
    const int w   = tid >> 6;      // wave 0..3, owns 16 q rows
    const int l   = tid & 63;
    const int lr  = l & 15;
    const int lh  = l >> 4;

    // block mapping: XCD pin + complementary tile lengths per CU slot group
    const int bx = blockIdx.x;     // 0..1023
    const int x  = bx & 7;         // XCD (heuristic: dispatch round-robins %8)
    const int m  = bx >> 3;        // 0..127
    const int hh = m & 3;
    const int j  = m >> 2;         // 0..31
    const int bh = hh * 8 + x;
    const int j0 = j & 7;
    const int ji = j >> 3;
    int t;
    switch (ji) {
        case 0:  t = j0;      break;
        case 1:  t = 15 - j0; break;
        case 2:  t = 16 + j0; break;
        default: t = 31 - j0; break;
    }
    const int nch = t + 1;
    const int q0  = t * 64;
    const int qg_base = q0 + w * 16 + lh * 4;    // + rr = this lane's q rows

    float* ctx_out  = out;                                   // [BH][S][D]
    float* attn_out = out + (size_t)N_BH * S_LEN * D_K;      // [BH][S][S]

    const ushort_t* Kb = Kws + (size_t)bh * S_LEN * D_K;     // [s][d], chunk c at c*4096
    const ushort_t* Vb = Vws + (size_t)bh * 32 * 4096;       // [c][d][k]

    // ---- Q fragments for my 16 rows, hi/lo bf16 split ----
    short8 qhi[2], qlo[2];
    {
        const float* qrow = Q + ((size_t)bh * S_LEN + q0 + w * 16 + lr) * D_K;
        #pragma unroll
        for (int ds = 0; ds < 2; ++ds) {
            const float4* p4 = (const float4*)(qrow + ds * 32 + lh * 8);
            float4 a = p4[0], bq = p4[1];
            float xx[8] = {a.x, a.y, a.z, a.w, bq.x, bq.y, bq.z, bq.w};
            short8 hi, lo;
            #pragma unroll
            for (int jj = 0; jj < 8; ++jj) {
                unsigned short h = f2bf(xx[jj]);
                hi[jj] = (short)h;
                lo[jj] = (short)f2bf(xx[jj] - bf2f(h));
            }
            qhi[ds] = hi; qlo[ds] = lo;
        }
    }

    // per-lane element offset inside a 64x64 chunk for fragment (nt, ks):
    // (nt*16 + lr)*64 + ks*32 + lh*8  (8 consecutive bf16 = 16 B per lane)
    const int fbase = lr * 64 + lh * 8;

    // ================= PASS 1: row sums (hi-only QK, no barriers) =================
    float inv_[4];
    {
        float sum[4] = {0.f, 0.f, 0.f, 0.f};
        for (int c = 0; c < nch; ++c) {
            const ushort_t* kc = Kb + (size_t)c * 4096;
            short8 bk[8];
            #pragma unroll
            for (int nt = 0; nt < 4; ++nt)
                #pragma unroll
                for (int ks = 0; ks < 2; ++ks)
                    bk[nt * 2 + ks] = *(const short8*)(kc + fbase + nt * 1024 + ks * 32);
            #pragma unroll
            for (int nt = 0; nt < 4; ++nt) {
                f32x4 acc = {0.f, 0.f, 0.f, 0.f};
                #pragma unroll
                for (int ks = 0; ks < 2; ++ks)
                    acc = __builtin_amdgcn_mfma_f32_16x16x32_bf16(qhi[ks], bk[nt * 2 + ks], acc, 0, 0, 0);
                const int kg = c * KB + nt * 16 + lr;
                #pragma unroll
                for (int rr = 0; rr < 4; ++rr)
                    if (kg <= qg_base + rr) sum[rr] += __expf(fminf(acc[rr], 60.f));
            }
        }
        #pragma unroll
        for (int rr = 0; rr < 4; ++rr) {   // butterfly over the 16 col-lanes
            float s = sum[rr];
            s += __shfl_xor(s, 1);
            s += __shfl_xor(s, 2);
            s += __shfl_xor(s, 4);
            s += __shfl_xor(s, 8);
            inv_[rr] = 1.f / s;
        }
    }

    // ================= PASS 2: attn write + PV (hi/lo QK, no barriers) =================
    f32x4 ctx[4];
    #pragma unroll
    for (int nt = 0; nt < 4; ++nt) ctx[nt] = (f32x4){0.f, 0.f, 0.f, 0.f};

    for (int c = 0; c < nch; ++c) {
        const ushort_t* kc = Kb + (size_t)c * 4096;
        const ushort_t* vc = Vb + (size_t)c * 4096;

        short8 bk[8];
        #pragma unroll
        for (int nt = 0; nt < 4; ++nt)
            #pragma unroll
            for (int ks = 0; ks < 2; ++ks)
                bk[nt * 2 + ks] = *(const short8*)(kc + fbase + nt * 1024 + ks * 32);

        #pragma unroll
        for (int nt = 0; nt < 4; ++nt) {
            f32x4 acc = {0.f, 0.f, 0.f, 0.f};
            #pragma unroll
            for (int ks = 0; ks < 2; ++ks) {
                acc = __builtin_amdgcn_mfma_f32_16x16x32_bf16(qhi[ks], bk[nt * 2 + ks], acc, 0, 0, 0);
                acc = __builtin_amdgcn_mfma_f32_16x16x32_bf16(qlo[ks], bk[nt * 2 + ks], acc, 0, 0, 0);
            }
            const int kg = c * KB + nt * 16 + lr;
            #pragma unroll
            for (int rr = 0; rr < 4; ++rr) {
                const int pwr = lh * 4 + rr;
                const int qg  = qg_base + rr;
                float p = (kg <= qg) ? __expf(fminf(acc[rr], 60.f)) * inv_[rr] : 0.f;
                attn_out[((size_t)bh * S_LEN + qg) * S_LEN + kg] = p;
                Plds[w][pwr * 64 + ((nt * 16 + lr) ^ ((pwr & 7) << 3))] = f2bf(p);
            }
        }

        short8 vb[8];
        #pragma unroll
        for (int nt = 0; nt < 4; ++nt)
            #pragma unroll
            for (int ks = 0; ks < 2; ++ks)
                vb[nt * 2 + ks] = *(const short8*)(vc + fbase + nt * 1024 + ks * 32);

        // PV from wave-private Plds (compiler inserts lgkmcnt; no barrier needed)
        short8 pa0 = *(const short8*)&Plds[w][lr * 64 + ((lh * 8) ^ ((lr & 7) << 3))];
        short8 pa1 = *(const short8*)&Plds[w][lr * 64 + ((32 + lh * 8) ^ ((lr & 7) << 3))];
        #pragma unroll
        for (int nt = 0; nt < 4; ++nt) {
            ctx[nt] = __builtin_amdgcn_mfma_f32_16x16x32_bf16(pa0, vb[nt * 2 + 0], ctx[nt], 0, 0, 0);
            ctx[nt] = __builtin_amdgcn_mfma_f32_16x16x32_bf16(pa1, vb[nt * 2 + 1], ctx[nt], 0, 0, 0);
        }
    }

    // context stores: my 16 rows x full 64 cols
    #pragma unroll
    for (int nt = 0; nt < 4; ++nt)
        #pragma unroll
        for (int rr = 0; rr < 4; ++rr)
            ctx_out[((size_t)bh * S_LEN + qg_base + rr) * D_K + nt * 16 + lr] = ctx[nt][rr];

    // zero-fill fully-masked tail columns (64 rows, 4 threads/row)
    const int k0 = nch * KB;
    if (k0 < S_LEN) {
        const float4 z = {0.f, 0.f, 0.f, 0.f};
        float* rowp = attn_out + ((size_t)bh * S_LEN + q0 + (tid >> 2)) * S_LEN;
        for (int k = k0 + (tid & 3) * 4; k < S_LEN; k += 16)
            *(float4*)(rowp + k) = z;
    }
}

// ===================== fallback (round-1 kernel, no ws) =====================
constexpr int LDP = 72;

__global__ __launch_bounds__(256)
void sdpa_fused_v1(const float* __restrict__ Q, const float* __restrict__ K,
                   const float* __restrict__ V, float* __restrict__ out)
{
    __shared__ __align__(16) unsigned short Klds[KB * LDP];
    __shared__ __align__(16) unsigned short Vtlds[D_K * LDP];
    __shared__ __align__(16) unsigned short Pl[4][16 * LDP];

    const int tid = threadIdx.x;
    const int w   = tid >> 6;
    const int l   = tid & 63;
    const int lr  = l & 15;
    const int lh  = l >> 4;

    const int bh   = blockIdx.y;
    const int qblk = (int)gridDim.x - 1 - (int)blockIdx.x;
    const int q0   = qblk * 64;
    const int qw   = q0 + w * 16;
    const int nchunks = qblk + 1;

    const size_t in_base = (size_t)bh * S_LEN * D_K;
    float* ctx_out  = out;
    float* attn_out = out + (size_t)N_BH * S_LEN * D_K;

    short8 qhi[2], qlo[2];
    {
        const float* qrow = Q + in_base + (size_t)(qw + lr) * D_K;
        #pragma unroll
        for (int ds = 0; ds < 2; ++ds) {
            const float4* p4 = (const float4*)(qrow + ds * 32 + lh * 8);
            float4 a = p4[0], b = p4[1];
            float x[8] = {a.x, a.y, a.z, a.w, b.x, b.y, b.z, b.w};
            short8 hi, lo;
            #pragma unroll
            for (int j = 0; j < 8; ++j) {
                unsigned short h = f2bf(x[j]);
                hi[j] = (short)h;
                lo[j] = (short)f2bf(x[j] - bf2f(h));
            }
            qhi[ds] = hi; qlo[ds] = lo;
        }
    }

    const int srow = tid >> 2;
    const int scol = (tid & 3) * 16;
    const float* kstage = K + in_base + (size_t)srow * D_K + scol;
    const float* vstage = V + in_base + (size_t)srow * D_K + scol;

    float inv_[4];
    {
        float sum[4] = {0.f, 0.f, 0.f, 0.f};
        for (int c = 0; c < nchunks; ++c) {
            {
                const float4* kp = (const float4*)(kstage + (size_t)c * KB * D_K);
                float4 a0 = kp[0], a1 = kp[1], a2 = kp[2], a3 = kp[3];
                float x[16] = {a0.x,a0.y,a0.z,a0.w, a1.x,a1.y,a1.z,a1.w,
                               a2.x,a2.y,a2.z,a2.w, a3.x,a3.y,a3.z,a3.w};
                short8 w0, w1;
                #pragma unroll
                for (int j = 0; j < 8; ++j) {
                    w0[j] = (short)f2bf(x[j]     * 0.125f);
                    w1[j] = (short)f2bf(x[j + 8] * 0.125f);
                }
                *(short8*)&Klds[srow * LDP + scol]     = w0;
                *(short8*)&Klds[srow * LDP + scol + 8] = w1;
            }
            __syncthreads();
            #pragma unroll
            for (int nt = 0; nt < 4; ++nt) {
                f32x4 acc = {0.f, 0.f, 0.f, 0.f};
                #pragma unroll
                for (int ks = 0; ks < 2; ++ks) {
                    short8 bk = *(const short8*)&Klds[(nt*16 + lr) * LDP + ks*32 + lh*8];
                    acc = __builtin_amdgcn_mfma_f32_16x16x32_bf16(qhi[ks], bk, acc, 0, 0, 0);
                    acc = __builtin_amdgcn_mfma_f32_16x16x32_bf16(qlo[ks], bk, acc, 0, 0, 0);
                }
                const int kg = c * KB + nt * 16 + lr;
                #pragma unroll
                for (int rr = 0; rr < 4; ++rr) {
                    if (kg <= qw + lh * 4 + rr)
                        sum[rr] += __expf(fminf(acc[rr], 60.f));
                }
            }
            __syncthreads();
        }
        #pragma unroll
        for (int rr = 0; rr < 4; ++rr) {
            float t = sum[rr];
            t += __shfl_xor(t, 1);
            t += __shfl_xor(t, 2);
            t += __shfl_xor(t, 4);
            t += __shfl_xor(t, 8);
            inv_[rr] = 1.f / t;
        }
    }

    f32x4 ctx[4];
    #pragma unroll
    for (int nt = 0; nt < 4; ++nt) ctx[nt] = (f32x4){0.f, 0.f, 0.f, 0.f};

    for (int c = 0; c < nchunks; ++c) {
        {
            const float4* kp = (const float4*)(kstage + (size_t)c * KB * D_K);
            float4 a0 = kp[0], a1 = kp[1], a2 = kp[2], a3 = kp[3];
            float x[16] = {a0.x,a0.y,a0.z,a0.w, a1.x,a1.y,a1.z,a1.w,
                           a2.x,a2.y,a2.z,a2.w, a3.x,a3.y,a3.z,a3.w};
            short8 w0, w1;
            #pragma unroll
            for (int j = 0; j < 8; ++j) {
                w0[j] = (short)f2bf(x[j]     * 0.125f);
                w1[j] = (short)f2bf(x[j + 8] * 0.125f);
            }
            *(short8*)&Klds[srow * LDP + scol]     = w0;
            *(short8*)&Klds[srow * LDP + scol + 8] = w1;

            const float4* vp = (const float4*)(vstage + (size_t)c * KB * D_K);
            float4 b0 = vp[0], b1 = vp[1], b2 = vp[2], b3 = vp[3];
            float y[16] = {b0.x,b0.y,b0.z,b0.w, b1.x,b1.y,b1.z,b1.w,
                           b2.x,b2.y,b2.z,b2.w, b3.x,b3.y,b3.z,b3.w};
            #pragma unroll
            for (int j = 0; j < 16; ++j)
                Vtlds[(scol + j) * LDP + srow] = f2bf(y[j]);
        }
        __syncthreads();

        #pragma unroll
        for (int nt = 0; nt < 4; ++nt) {
            f32x4 acc = {0.f, 0.f, 0.f, 0.f};
            #pragma unroll
            for (int ks = 0; ks < 2; ++ks) {
                short8 bk = *(const short8*)&Klds[(nt*16 + lr) * LDP + ks*32 + lh*8];
                acc = __builtin_amdgcn_mfma_f32_16x16x32_bf16(qhi[ks], bk, acc, 0, 0, 0);
                acc = __builtin_amdgcn_mfma_f32_16x16x32_bf16(qlo[ks], bk, acc, 0, 0, 0);
            }
            const int kg = c * KB + nt * 16 + lr;
            #pragma unroll
            for (int rr = 0; rr < 4; ++rr) {
                const int qg = qw + lh * 4 + rr;
                float p = (kg <= qg) ? __expf(fminf(acc[rr], 60.f)) * inv_[rr] : 0.f;
                attn_out[((size_t)bh * S_LEN + qg) * S_LEN + kg] = p;
                Pl[w][(lh * 4 + rr) * LDP + nt * 16 + lr] = f2bf(p);
            }
        }
        __syncthreads();

        #pragma unroll
        for (int ks = 0; ks < 2; ++ks) {
            short8 pa = *(const short8*)&Pl[w][lr * LDP + ks*32 + lh*8];
            #pragma unroll
            for (int nt = 0; nt < 4; ++nt) {
                short8 vb = *(const short8*)&Vtlds[(nt*16 + lr) * LDP + ks*32 + lh*8];
                ctx[nt] = __builtin_amdgcn_mfma_f32_16x16x32_bf16(pa, vb, ctx[nt], 0, 0, 0);
            }
        }
        __syncthreads();
    }

    #pragma unroll
    for (int nt = 0; nt < 4; ++nt)
        #pragma unroll
        for (int rr = 0; rr < 4; ++rr)
            ctx_out[((size_t)bh * S_LEN + qw + lh * 4 + rr) * D_K + nt * 16 + lr] = ctx[nt][rr];

    const int k0 = nchunks * KB;
    if (k0 < S_LEN) {
        const float4 z = {0.f, 0.f, 0.f, 0.f};
        for (int rr = 0; rr < 64; ++rr) {
            float* rowp = attn_out + ((size_t)bh * S_LEN + q0 + rr) * S_LEN;
            for (int k = k0 + tid * 4; k < S_LEN; k += 256 * 4)
                *(float4*)(rowp + k) = z;
        }
    }
}

extern "C" void kernel_launch(void* const* d_in, const int* in_sizes, int n_in,
                              void* d_out, int out_size, void* d_ws, size_t ws_size,
                              hipStream_t stream)
{
    const float* Q = (const float*)d_in[0];
    const float* K = (const float*)d_in[1];
    const float* V = (const float*)d_in[2];
    float* out = (float*)d_out;

    const size_t ws_needed = (size_t)2 * N_BH * S_LEN * D_K * sizeof(ushort_t);  // 16.8 MB
    if (ws_size >= ws_needed) {
        ushort_t* Kws = (ushort_t*)d_ws;
        ushort_t* Vws = Kws + (size_t)N_BH * S_LEN * D_K;
        prep_k<<<2048, 256, 0, stream>>>(K, Kws);
        prep_v<<<2048, 256, 0, stream>>>(V, Vws);
        sdpa_main<<<1024, 256, 0, stream>>>(Q, Kws, Vws, out);
    } else {
        dim3 grid(S_LEN / 64, N_BH);
        sdpa_fused_v1<<<grid, 256, 0, stream>>>(Q, K, V, out);
    }
}

// Round 8
// 186.821 us; speedup vs baseline: 1.3960x; 1.3960x over previous
//
#include <hip/hip_runtime.h>

constexpr int S_LEN = 2048;
constexpr int D_K   = 64;
constexpr int N_BH  = 32;   // B*H
constexpr int KB    = 64;   // k per chunk

typedef __attribute__((ext_vector_type(8))) short short8;
typedef __attribute__((ext_vector_type(4))) short short4_t;
typedef __attribute__((ext_vector_type(4))) float f32x4;
typedef unsigned short ushort_t;

__device__ __forceinline__ unsigned short f2bf(float f) {
    unsigned int u = __builtin_bit_cast(unsigned int, f);
    u += 0x7fffu + ((u >> 16) & 1u);          // round-to-nearest-even
    return (unsigned short)(u >> 16);
}
__device__ __forceinline__ float bf2f(unsigned short h) {
    unsigned int u = ((unsigned int)h) << 16;
    return __builtin_bit_cast(float, u);
}

// ============================ prep kernels ============================
__global__ __launch_bounds__(256)
void prep_k(const float* __restrict__ K, ushort_t* __restrict__ Kws) {
    const int idx = blockIdx.x * 256 + threadIdx.x;
    const float4* src = (const float4*)K + (size_t)idx * 2;
    float4 a = src[0], b = src[1];
    float x[8] = {a.x, a.y, a.z, a.w, b.x, b.y, b.z, b.w};
    short8 o;
    #pragma unroll
    for (int j = 0; j < 8; ++j) o[j] = (short)f2bf(x[j] * 0.125f);
    *(short8*)(Kws + (size_t)idx * 8) = o;
}

__global__ __launch_bounds__(256)
void prep_v(const float* __restrict__ V, ushort_t* __restrict__ Vws) {
    const int gid = blockIdx.x * 256 + threadIdx.x;
    const int u   = gid & 511;
    const int bc  = gid >> 9;
    const int c   = bc & 31;
    const int bh  = bc >> 5;
    const int kg  = u >> 6;
    const int d   = u & 63;
    const float* vp = V + ((size_t)bh * S_LEN + c * KB + kg * 8) * D_K + d;
    short8 o;
    #pragma unroll
    for (int i = 0; i < 8; ++i) o[i] = (short)f2bf(vp[(size_t)i * D_K]);
    *(short8*)(Vws + ((size_t)(bh * 32 + c) * D_K + d) * KB + kg * 8) = o;
}

// ============================ main kernel =============================
// R6 structure (best: 173 us) with ONE change: all attn stores are full-line.
// Main store: re-read P from Plds (bf16) with row=l>>4, col=(l&15)*4 mapping ->
// float4/lane, 16 lanes x 16 B = 256 B contiguous per row (2 full 128 B lines
// per instruction-row) -> no L2 write-allocate fetch from HBM.
// Zero-fill: 8 lanes x float4 = 128 B per row per instruction.
__global__ __launch_bounds__(256, 4)
void sdpa_main(const float* __restrict__ Q, const ushort_t* __restrict__ Kws,
               const ushort_t* __restrict__ Vws, float* __restrict__ out)
{
    __shared__ __align__(16) ushort_t Kbuf[2][4096];   // 16 KB
    __shared__ __align__(16) ushort_t Vbuf[2][4096];   // 16 KB
    __shared__ __align__(16) ushort_t Plds[4][1024];   //  8 KB (per-wave 16x64)

    const int tid = threadIdx.x;
    const int w   = tid >> 6;      // wave 0..3, owns 16 q rows
    const int l   = tid & 63;
    const int lr  = l & 15;
    const int lh  = l >> 4;

    // tile mapping: slots r=0..7 per group g; groups give t = r, 15-r, 16+r, 31-r
    const int bx  = blockIdx.x;    // 0..1023
    const int g   = bx >> 8;
    const int idx = bx & 255;
    const int bh  = idx >> 3;
    const int r   = idx & 7;
    int t;
    switch (g) {
        case 0:  t = r;      break;
        case 1:  t = 15 - r; break;
        case 2:  t = 16 + r; break;
        default: t = 31 - r; break;
    }
    const int nch = t + 1;
    const int q0  = t * 64;
    const int qg_base = q0 + w * 16 + lh * 4;    // + rr = this lane's q rows

    float* ctx_out  = out;                                   // [BH][S][D]
    float* attn_out = out + (size_t)N_BH * S_LEN * D_K;      // [BH][S][S]

    const short8* Kt  = (const short8*)(Kws + (size_t)bh * S_LEN * D_K);   // chunk c at c*512
    const short8* Vt8 = (const short8*)(Vws + (size_t)bh * 32 * 4096);

    // staging: thread writes units tid and tid+256 of each 512-unit chunk
    const int wrow0  = tid >> 3;                  // 0..31
    const int wcol   = (tid & 7) << 4;
    const int wphys0 = wrow0 * 128 + (wcol ^ ((wrow0 & 7) << 4));
    const int wphys1 = wphys0 + 32 * 128;         // rows 32..63, same (row&7)
    const int rsw    = (lr & 7) << 4;             // K/V frag-read swizzle (bytes)

    // ---- Q fragments for my 16 rows, hi/lo bf16 split ----
    short8 qhi[2], qlo[2];
    {
        const float* qrow = Q + ((size_t)bh * S_LEN + q0 + w * 16 + lr) * D_K;
        #pragma unroll
        for (int ds = 0; ds < 2; ++ds) {
            const float4* p4 = (const float4*)(qrow + ds * 32 + lh * 8);
            float4 a = p4[0], bq = p4[1];
            float x[8] = {a.x, a.y, a.z, a.w, bq.x, bq.y, bq.z, bq.w};
            short8 hi, lo;
            #pragma unroll
            for (int j = 0; j < 8; ++j) {
                unsigned short h = f2bf(x[j]);
                hi[j] = (short)h;
                lo[j] = (short)f2bf(x[j] - bf2f(h));
            }
            qhi[ds] = hi; qlo[ds] = lo;
        }
    }

    // ================= PASS 1: row sums (single-bf16 QK) =================
    float inv_[4];
    {
        float sum[4] = {0.f, 0.f, 0.f, 0.f};

        auto p1 = [&](const char* Kb, int c) {
            #pragma unroll
            for (int nt = 0; nt < 4; ++nt) {
                f32x4 acc = {0.f, 0.f, 0.f, 0.f};
                #pragma unroll
                for (int ks = 0; ks < 2; ++ks) {
                    short8 bk = *(const short8*)(Kb + (nt * 16 + lr) * 128 + ((ks * 64 + lh * 16) ^ rsw));
                    acc = __builtin_amdgcn_mfma_f32_16x16x32_bf16(qhi[ks], bk, acc, 0, 0, 0);
                }
                const int kg = c * KB + nt * 16 + lr;
                #pragma unroll
                for (int rr = 0; rr < 4; ++rr)
                    if (kg <= qg_base + rr) sum[rr] += __expf(fminf(acc[rr], 60.f));
            }
        };

        short8 kE0 = Kt[tid], kE1 = Kt[tid + 256];             // chunk 0
        *(short8*)((char*)&Kbuf[0][0] + wphys0) = kE0;
        *(short8*)((char*)&Kbuf[0][0] + wphys1) = kE1;
        short8 kO0 = Kt[512 + tid], kO1 = Kt[512 + tid + 256]; // chunk 1 (always in-bounds)
        __syncthreads();
        for (int c = 0; c < nch; c += 2) {
            if (c + 2 < nch) { kE0 = Kt[(c + 2) * 512 + tid]; kE1 = Kt[(c + 2) * 512 + tid + 256]; }
            p1((const char*)&Kbuf[0][0], c);
            if (c + 1 < nch) {
                *(short8*)((char*)&Kbuf[1][0] + wphys0) = kO0;
                *(short8*)((char*)&Kbuf[1][0] + wphys1) = kO1;
            }
            __syncthreads();
            if (c + 1 < nch) {
                if (c + 3 < nch) { kO0 = Kt[(c + 3) * 512 + tid]; kO1 = Kt[(c + 3) * 512 + tid + 256]; }
                p1((const char*)&Kbuf[1][0], c + 1);
                if (c + 2 < nch) {
                    *(short8*)((char*)&Kbuf[0][0] + wphys0) = kE0;
                    *(short8*)((char*)&Kbuf[0][0] + wphys1) = kE1;
                }
                __syncthreads();
            }
        }
        #pragma unroll
        for (int rr = 0; rr < 4; ++rr) {   // butterfly over the 16 col-lanes
            float s = sum[rr];
            s += __shfl_xor(s, 1);
            s += __shfl_xor(s, 2);
            s += __shfl_xor(s, 4);
            s += __shfl_xor(s, 8);
            inv_[rr] = 1.f / s;
        }
    }

    // ================= PASS 2: attn write + PV (hi/lo QK) =================
    f32x4 ctx[4];
    #pragma unroll
    for (int nt = 0; nt < 4; ++nt) ctx[nt] = (f32x4){0.f, 0.f, 0.f, 0.f};

    // full-line store mapping: 4 rows/instr, 16 lanes x float4 = 256 B/row
    const int srow_l = l >> 4;          // 0..3
    const int scol_l = (l & 15) * 4;    // col base (floats)

    {
        auto p2 = [&](const char* Kb, const char* Vb, int c) {
            // QK^T + exp + stage normalized P (bf16) into private Plds
            #pragma unroll
            for (int nt = 0; nt < 4; ++nt) {
                f32x4 acc = {0.f, 0.f, 0.f, 0.f};
                #pragma unroll
                for (int ks = 0; ks < 2; ++ks) {
                    short8 bk = *(const short8*)(Kb + (nt * 16 + lr) * 128 + ((ks * 64 + lh * 16) ^ rsw));
                    acc = __builtin_amdgcn_mfma_f32_16x16x32_bf16(qhi[ks], bk, acc, 0, 0, 0);
                    acc = __builtin_amdgcn_mfma_f32_16x16x32_bf16(qlo[ks], bk, acc, 0, 0, 0);
                }
                const int kg = c * KB + nt * 16 + lr;
                #pragma unroll
                for (int rr = 0; rr < 4; ++rr) {
                    const int pwr = lh * 4 + rr;
                    const int qg  = qg_base + rr;
                    float p = (kg <= qg) ? __expf(fminf(acc[rr], 60.f)) * inv_[rr] : 0.f;
                    Plds[w][pwr * 64 + ((nt * 16 + lr) ^ ((pwr & 7) << 3))] = f2bf(p);
                }
            }
            // PV from private Plds
            #pragma unroll
            for (int ks = 0; ks < 2; ++ks) {
                short8 pa = *(const short8*)&Plds[w][lr * 64 + ((ks * 32 + lh * 8) ^ ((lr & 7) << 3))];
                #pragma unroll
                for (int nt = 0; nt < 4; ++nt) {
                    short8 vb = *(const short8*)(Vb + (nt * 16 + lr) * 128 + ((ks * 64 + lh * 16) ^ rsw));
                    ctx[nt] = __builtin_amdgcn_mfma_f32_16x16x32_bf16(pa, vb, ctx[nt], 0, 0, 0);
                }
            }
            // full-line attn store: re-read Plds, float4/lane, 256 B contiguous/row
            #pragma unroll
            for (int rg = 0; rg < 4; ++rg) {
                const int prow = rg * 4 + srow_l;
                short4_t p4 = *(const short4_t*)&Plds[w][prow * 64 + (scol_l ^ ((prow & 7) << 3))];
                float4 f4 = {bf2f((ushort_t)p4[0]), bf2f((ushort_t)p4[1]),
                             bf2f((ushort_t)p4[2]), bf2f((ushort_t)p4[3])};
                *(float4*)(attn_out + ((size_t)bh * S_LEN + q0 + w * 16 + prow) * S_LEN
                           + c * KB + scol_l) = f4;
            }
        };

        short8 kE0 = Kt[tid],        kE1 = Kt[tid + 256];
        short8 vE0 = Vt8[tid],       vE1 = Vt8[tid + 256];
        *(short8*)((char*)&Kbuf[0][0] + wphys0) = kE0;
        *(short8*)((char*)&Kbuf[0][0] + wphys1) = kE1;
        *(short8*)((char*)&Vbuf[0][0] + wphys0) = vE0;
        *(short8*)((char*)&Vbuf[0][0] + wphys1) = vE1;
        short8 kO0 = Kt[512 + tid],  kO1 = Kt[512 + tid + 256];
        short8 vO0 = Vt8[512 + tid], vO1 = Vt8[512 + tid + 256];
        __syncthreads();
        for (int c = 0; c < nch; c += 2) {
            if (c + 2 < nch) {
                kE0 = Kt[(c + 2) * 512 + tid];  kE1 = Kt[(c + 2) * 512 + tid + 256];
                vE0 = Vt8[(c + 2) * 512 + tid]; vE1 = Vt8[(c + 2) * 512 + tid + 256];
            }
            p2((const char*)&Kbuf[0][0], (const char*)&Vbuf[0][0], c);
            if (c + 1 < nch) {
                *(short8*)((char*)&Kbuf[1][0] + wphys0) = kO0;
                *(short8*)((char*)&Kbuf[1][0] + wphys1) = kO1;
                *(short8*)((char*)&Vbuf[1][0] + wphys0) = vO0;
                *(short8*)((char*)&Vbuf[1][0] + wphys1) = vO1;
            }
            __syncthreads();
            if (c + 1 < nch) {
                if (c + 3 < nch) {
                    kO0 = Kt[(c + 3) * 512 + tid];  kO1 = Kt[(c + 3) * 512 + tid + 256];
                    vO0 = Vt8[(c + 3) * 512 + tid]; vO1 = Vt8[(c + 3) * 512 + tid + 256];
                }
                p2((const char*)&Kbuf[1][0], (const char*)&Vbuf[1][0], c + 1);
                if (c + 2 < nch) {
                    *(short8*)((char*)&Kbuf[0][0] + wphys0) = kE0;
                    *(short8*)((char*)&Kbuf[0][0] + wphys1) = kE1;
                    *(short8*)((char*)&Vbuf[0][0] + wphys0) = vE0;
                    *(short8*)((char*)&Vbuf[0][0] + wphys1) = vE1;
                }
                __syncthreads();
            }
        }
    }

    // context stores: my 16 rows x full 64 cols
    #pragma unroll
    for (int nt = 0; nt < 4; ++nt)
        #pragma unroll
        for (int rr = 0; rr < 4; ++rr)
            ctx_out[((size_t)bh * S_LEN + qg_base + rr) * D_K + nt * 16 + lr] = ctx[nt][rr];

    // zero-fill fully-masked tail columns: 8 lanes x float4 = 128 B (full line) per row
    const int k0 = nch * KB;
    if (k0 < S_LEN) {
        const float4 z = {0.f, 0.f, 0.f, 0.f};
        #pragma unroll
        for (int rbase = 0; rbase < 64; rbase += 32) {
            float* rowp = attn_out + ((size_t)bh * S_LEN + q0 + rbase + (tid >> 3)) * S_LEN;
            for (int k = k0 + (tid & 7) * 4; k < S_LEN; k += 32)
                *(float4*)(rowp + k) = z;
        }
    }
}

// ===================== fallback (round-1 kernel, no ws) =====================
constexpr int LDP = 72;

__global__ __launch_bounds__(256)
void sdpa_fused_v1(const float* __restrict__ Q, const float* __restrict__ K,
                   const float* __restrict__ V, float* __restrict__ out)
{
    __shared__ __align__(16) unsigned short Klds[KB * LDP];
    __shared__ __align__(16) unsigned short Vtlds[D_K * LDP];
    __shared__ __align__(16) unsigned short Pl[4][16 * LDP];

    const int tid = threadIdx.x;
    const int w   = tid >> 6;
    const int l   = tid & 63;
    const int lr  = l & 15;
    const int lh  = l >> 4;

    const int bh   = blockIdx.y;
    const int qblk = (int)gridDim.x - 1 - (int)blockIdx.x;
    const int q0   = qblk * 64;
    const int qw   = q0 + w * 16;
    const int nchunks = qblk + 1;

    const size_t in_base = (size_t)bh * S_LEN * D_K;
    float* ctx_out  = out;
    float* attn_out = out + (size_t)N_BH * S_LEN * D_K;

    short8 qhi[2], qlo[2];
    {
        const float* qrow = Q + in_base + (size_t)(qw + lr) * D_K;
        #pragma unroll
        for (int ds = 0; ds < 2; ++ds) {
            const float4* p4 = (const float4*)(qrow + ds * 32 + lh * 8);
            float4 a = p4[0], b = p4[1];
            float x[8] = {a.x, a.y, a.z, a.w, b.x, b.y, b.z, b.w};
            short8 hi, lo;
            #pragma unroll
            for (int j = 0; j < 8; ++j) {
                unsigned short h = f2bf(x[j]);
                hi[j] = (short)h;
                lo[j] = (short)f2bf(x[j] - bf2f(h));
            }
            qhi[ds] = hi; qlo[ds] = lo;
        }
    }

    const int srow = tid >> 2;
    const int scol = (tid & 3) * 16;
    const float* kstage = K + in_base + (size_t)srow * D_K + scol;
    const float* vstage = V + in_base + (size_t)srow * D_K + scol;

    float inv_[4];
    {
        float sum[4] = {0.f, 0.f, 0.f, 0.f};
        for (int c = 0; c < nchunks; ++c) {
            {
                const float4* kp = (const float4*)(kstage + (size_t)c * KB * D_K);
                float4 a0 = kp[0], a1 = kp[1], a2 = kp[2], a3 = kp[3];
                float x[16] = {a0.x,a0.y,a0.z,a0.w, a1.x,a1.y,a1.z,a1.w,
                               a2.x,a2.y,a2.z,a2.w, a3.x,a3.y,a3.z,a3.w};
                short8 w0, w1;
                #pragma unroll
                for (int j = 0; j < 8; ++j) {
                    w0[j] = (short)f2bf(x[j]     * 0.125f);
                    w1[j] = (short)f2bf(x[j + 8] * 0.125f);
                }
                *(short8*)&Klds[srow * LDP + scol]     = w0;
                *(short8*)&Klds[srow * LDP + scol + 8] = w1;
            }
            __syncthreads();
            #pragma unroll
            for (int nt = 0; nt < 4; ++nt) {
                f32x4 acc = {0.f, 0.f, 0.f, 0.f};
                #pragma unroll
                for (int ks = 0; ks < 2; ++ks) {
                    short8 bk = *(const short8*)&Klds[(nt*16 + lr) * LDP + ks*32 + lh*8];
                    acc = __builtin_amdgcn_mfma_f32_16x16x32_bf16(qhi[ks], bk, acc, 0, 0, 0);
                    acc = __builtin_amdgcn_mfma_f32_16x16x32_bf16(qlo[ks], bk, acc, 0, 0, 0);
                }
                const int kg = c * KB + nt * 16 + lr;
                #pragma unroll
                for (int rr = 0; rr < 4; ++rr) {
                    if (kg <= qw + lh * 4 + rr)
                        sum[rr] += __expf(fminf(acc[rr], 60.f));
                }
            }
            __syncthreads();
        }
        #pragma unroll
        for (int rr = 0; rr < 4; ++rr) {
            float t = sum[rr];
            t += __shfl_xor(t, 1);
            t += __shfl_xor(t, 2);
            t += __shfl_xor(t, 4);
            t += __shfl_xor(t, 8);
            inv_[rr] = 1.f / t;
        }
    }

    f32x4 ctx[4];
    #pragma unroll
    for (int nt = 0; nt < 4; ++nt) ctx[nt] = (f32x4){0.f, 0.f, 0.f, 0.f};

    for (int c = 0; c < nchunks; ++c) {
        {
            const float4* kp = (const float4*)(kstage + (size_t)c * KB * D_K);
            float4 a0 = kp[0], a1 = kp[1], a2 = kp[2], a3 = kp[3];
            float x[16] = {a0.x,a0.y,a0.z,a0.w, a1.x,a1.y,a1.z,a1.w,
                           a2.x,a2.y,a2.z,a2.w, a3.x,a3.y,a3.z,a3.w};
            short8 w0, w1;
            #pragma unroll
            for (int j = 0; j < 8; ++j) {
                w0[j] = (short)f2bf(x[j]     * 0.125f);
                w1[j] = (short)f2bf(x[j + 8] * 0.125f);
            }
            *(short8*)&Klds[srow * LDP + scol]     = w0;
            *(short8*)&Klds[srow * LDP + scol + 8] = w1;

            const float4* vp = (const float4*)(vstage + (size_t)c * KB * D_K);
            float4 b0 = vp[0], b1 = vp[1], b2 = vp[2], b3 = vp[3];
            float y[16] = {b0.x,b0.y,b0.z,b0.w, b1.x,b1.y,b1.z,b1.w,
                           b2.x,b2.y,b2.z,b2.w, b3.x,b3.y,b3.z,b3.w};
            #pragma unroll
            for (int j = 0; j < 16; ++j)
                Vtlds[(scol + j) * LDP + srow] = f2bf(y[j]);
        }
        __syncthreads();

        #pragma unroll
        for (int nt = 0; nt < 4; ++nt) {
            f32x4 acc = {0.f, 0.f, 0.f, 0.f};
            #pragma unroll
            for (int ks = 0; ks < 2; ++ks) {
                short8 bk = *(const short8*)&Klds[(nt*16 + lr) * LDP + ks*32 + lh*8];
                acc = __builtin_amdgcn_mfma_f32_16x16x32_bf16(qhi[ks], bk, acc, 0, 0, 0);
                acc = __builtin_amdgcn_mfma_f32_16x16x32_bf16(qlo[ks], bk, acc, 0, 0, 0);
            }
            const int kg = c * KB + nt * 16 + lr;
            #pragma unroll
            for (int rr = 0; rr < 4; ++rr) {
                const int qg = qw + lh * 4 + rr;
                float p = (kg <= qg) ? __expf(fminf(acc[rr], 60.f)) * inv_[rr] : 0.f;
                attn_out[((size_t)bh * S_LEN + qg) * S_LEN + kg] = p;
                Pl[w][(lh * 4 + rr) * LDP + nt * 16 + lr] = f2bf(p);
            }
        }
        __syncthreads();

        #pragma unroll
        for (int ks = 0; ks < 2; ++ks) {
            short8 pa = *(const short8*)&Pl[w][lr * LDP + ks*32 + lh*8];
            #pragma unroll
            for (int nt = 0; nt < 4; ++nt) {
                short8 vb = *(const short8*)&Vtlds[(nt*16 + lr) * LDP + ks*32 + lh*8];
                ctx[nt] = __builtin_amdgcn_mfma_f32_16x16x32_bf16(pa, vb, ctx[nt], 0, 0, 0);
            }
        }
        __syncthreads();
    }

    #pragma unroll
    for (int nt = 0; nt < 4; ++nt)
        #pragma unroll
        for (int rr = 0; rr < 4; ++rr)
            ctx_out[((size_t)bh * S_LEN + qw + lh * 4 + rr) * D_K + nt * 16 + lr] = ctx[nt][rr];

    const int k0 = nchunks * KB;
    if (k0 < S_LEN) {
        const float4 z = {0.f, 0.f, 0.f, 0.f};
        for (int rr = 0; rr < 64; ++rr) {
            float* rowp = attn_out + ((size_t)bh * S_LEN + q0 + rr) * S_LEN;
            for (int k = k0 + tid * 4; k < S_LEN; k += 256 * 4)
                *(float4*)(rowp + k) = z;
        }
    }
}

extern "C" void kernel_launch(void* const* d_in, const int* in_sizes, int n_in,
                              void* d_out, int out_size, void* d_ws, size_t ws_size,
                              hipStream_t stream)
{
    const float* Q = (const float*)d_in[0];
    const float* K = (const float*)d_in[1];
    const float* V = (const float*)d_in[2];
    float* out = (float*)d_out;

    const size_t ws_needed = (size_t)2 * N_BH * S_LEN * D_K * sizeof(ushort_t);  // 16.8 MB
    if (ws_size >= ws_needed) {
        ushort_t* Kws = (ushort_t*)d_ws;
        ushort_t* Vws = Kws + (size_t)N_BH * S_LEN * D_K;
        prep_k<<<2048, 256, 0, stream>>>(K, Kws);
        prep_v<<<2048, 256, 0, stream>>>(V, Vws);
        sdpa_main<<<1024, 256, 0, stream>>>(Q, Kws, Vws, out);
    } else {
        dim3 grid(S_LEN / 64, N_BH);
        sdpa_fused_v1<<<grid, 256, 0, stream>>>(Q, K, V, out);
    }
}